// Round 12
// baseline (111.300 us; speedup 1.0000x reference)
//
#include <hip/hip_runtime.h>
#include <math.h>

#define BB   512
#define TT   256
#define EMBD 364
#define HS   64
#define KPAD 384
#define NC   192

typedef __attribute__((ext_vector_type(8))) short short8_t;  // 8 bf16
typedef __attribute__((ext_vector_type(4))) float f32x4;

__device__ __forceinline__ ushort f2bf(float v) {
    union { float f; unsigned u; } c; c.f = v;
    unsigned b = c.u;
    return (ushort)((b + 0x7FFF + ((b >> 16) & 1)) >> 16);   // RNE
}
__device__ __forceinline__ ushort f2bfc(float v) {           // cheap round (A-frags only)
    union { float f; unsigned u; } c; c.f = v;
    return (ushort)((c.u + 0x8000u) >> 16);
}

// async global->LDS, 16B per lane: lane l writes LP + l*16 (dest wave-uniform base)
#define GLOAD_LDS16(GP, LP)                                                       \
    __builtin_amdgcn_global_load_lds(                                             \
        (const __attribute__((address_space(1))) void*)(const void*)(GP),         \
        (__attribute__((address_space(3))) void*)(void*)(LP), 16, 0, 0)

// ---------------- d_ws layout (bytes) ----------------
#define WTR_BYTES ((size_t)144 * 512 * 2)            // 147456 (B-frag-ordered W)
#define KQ_ELEMS  ((size_t)BB * TT * HS)             // 8388608
#define K_OFF_B   (WTR_BYTES)
#define Q_OFF_B   (K_OFF_B + KQ_ELEMS * 2)
#define VT_OFF_B  (Q_OFF_B + KQ_ELEMS * 2)

// ---------- kernel 0: W -> B-fragment-ordered bf16 WTr, k-part pre-scaled ----------
__global__ void prep_wtr(const float* __restrict__ Wk, const float* __restrict__ Wq,
                         const float* __restrict__ Wv, ushort* __restrict__ WTr)
{
    const int bid = blockIdx.x;          // 0..143 = jj*12 + t
    const int jj  = bid / 12;
    const int t   = bid % 12;
    const int l   = threadIdx.x;
    const int c   = jj * 16 + (l & 15);
    const float* Wp = (c < 64) ? Wk : (c < 128 ? Wq : Wv);
    const float s   = (c < 64) ? 0.125f : 1.0f;
    const int col   = c & 63;
    #pragma unroll
    for (int i = 0; i < 8; ++i) {
        int k = t * 32 + (l >> 4) * 8 + i;
        float v = (k < EMBD) ? Wp[(size_t)k * HS + col] * s : 0.f;   // zero pad k>=364
        WTr[((size_t)bid * 64 + l) * 8 + i] = f2bf(v);
    }
}

// ================= Kernel A: single-burst whole-K projection GEMM =================
// 4096 blocks x 256 thr (4 waves). Block: 32 M-rows, full K=384 fp32 staged in ONE
// burst of 48 width-16 global_load_lds (12/wave), ONE barrier, then 72 MFMA/wave.
// LDS tile: flat [32 rows][96 quads], quad-XOR swizzled (p = q ^ (row&7)) via
// pre-swizzled per-lane SOURCE addresses (dest stays linear) -> 2-way banks (free).
__global__ __launch_bounds__(256, 3) void proj_gemm(
    const float* __restrict__ x, const ushort* __restrict__ WTr,
    const float* __restrict__ bk_, const float* __restrict__ bq_,
    const float* __restrict__ bv_,
    ushort* __restrict__ Kg, ushort* __restrict__ Qg, ushort* __restrict__ Vt)
{
    const int blk = blockIdx.x;
    const int tid = threadIdx.x;
    const int l   = tid & 63;
    const int w   = tid >> 6;
    const int l15 = l & 15;
    const int lg  = l >> 4;

    __shared__ float xf[32 * KPAD];     // 48 KB, flat; row r quad p at byte r*1536+p*16

    const float* xb = x + (size_t)blk * 32 * EMBD;

    // ---- single-burst stage: wave w issues instrs g = w*12 .. w*12+11 ----
    #pragma unroll
    for (int gi = 0; gi < 12; ++gi) {
        const int g     = w * 12 + gi;
        const unsigned flatP = (unsigned)(g * 64 + l); // physical quad index in tile
        const unsigned row   = flatP / 96u;            // 0..31
        const unsigned p     = flatP % 96u;            // physical within-row quad
        const unsigned q     = p ^ (row & 7u);         // logical quad (source swizzle)
        const unsigned colq  = (q < 91u) ? q : 0u;     // clamp tail; B rows zeroed
        const float* gp = xb + (size_t)row * EMBD + colq * 4u;
        GLOAD_LDS16(gp, (char*)xf + (size_t)g * 1024);
    }

    float bias3[3];
    #pragma unroll
    for (int j = 0; j < 3; ++j) {
        int c = w * 48 + j * 16 + l15;
        bias3[j] = (c < 64) ? bk_[c] * 0.125f : (c < 128 ? bq_[c - 64] : bv_[c - 128]);
    }

    f32x4 acc[2][3];
    #pragma unroll
    for (int mi = 0; mi < 2; ++mi)
        #pragma unroll
        for (int j = 0; j < 3; ++j) acc[mi][j] = (f32x4){0.f, 0.f, 0.f, 0.f};

    __syncthreads();    // single drain: all 48 KB resident

    // ---- compute: 12 ks-subchunks (K=32 each) x 2 mi x 3 j ----
    #pragma unroll
    for (int ks = 0; ks < 12; ++ks) {
        short8_t Bf[3];
        #pragma unroll
        for (int j = 0; j < 3; ++j)
            Bf[j] = *(const short8_t*)&WTr[(((size_t)(w * 3 + j) * 12 + ks) * 64 + l) * 8];
        #pragma unroll
        for (int mi = 0; mi < 2; ++mi) {
            const unsigned row = mi * 16 + l15;
            const unsigned q0  = ks * 8 + lg * 2;          // logical quad of frag lo half
            const unsigned p0  = q0 ^ (row & 7u);
            const unsigned p1  = (q0 + 1u) ^ (row & 7u);
            f32x4 A0 = *(const f32x4*)&xf[row * KPAD + p0 * 4u];
            f32x4 A1 = *(const f32x4*)&xf[row * KPAD + p1 * 4u];
            union { short8_t s8; ushort us[8]; } pk;
            pk.us[0] = f2bfc(A0[0]); pk.us[1] = f2bfc(A0[1]);
            pk.us[2] = f2bfc(A0[2]); pk.us[3] = f2bfc(A0[3]);
            pk.us[4] = f2bfc(A1[0]); pk.us[5] = f2bfc(A1[1]);
            pk.us[6] = f2bfc(A1[2]); pk.us[7] = f2bfc(A1[3]);
            #pragma unroll
            for (int j = 0; j < 3; ++j)
                acc[mi][j] = __builtin_amdgcn_mfma_f32_16x16x32_bf16(pk.s8, Bf[j], acc[mi][j], 0, 0, 0);
        }
    }

    // ---- epilogue: +bias, K/Q row-major, V transposed per batch ----
    const int b   = blk >> 3;
    const int tl0 = (blk & 7) * 32;
    #pragma unroll
    for (int j = 0; j < 3; ++j) {
        const int c = w * 48 + j * 16 + l15;
        #pragma unroll
        for (int mi = 0; mi < 2; ++mi) {
            if (c < 64) {
                #pragma unroll
                for (int r = 0; r < 4; ++r) {
                    const size_t trow = (size_t)blk * 32 + mi * 16 + lg * 4 + r;
                    Kg[trow * HS + c] = f2bf(acc[mi][j][r] + bias3[j]);
                }
            } else if (c < 128) {
                #pragma unroll
                for (int r = 0; r < 4; ++r) {
                    const size_t trow = (size_t)blk * 32 + mi * 16 + lg * 4 + r;
                    Qg[trow * HS + (c - 64)] = f2bf(acc[mi][j][r] + bias3[j]);
                }
            } else {
                ushort4 pk;
                pk.x = f2bf(acc[mi][j][0] + bias3[j]);
                pk.y = f2bf(acc[mi][j][1] + bias3[j]);
                pk.z = f2bf(acc[mi][j][2] + bias3[j]);
                pk.w = f2bf(acc[mi][j][3] + bias3[j]);
                *(ushort4*)&Vt[((size_t)b * HS + (c - 128)) * TT + tl0 + mi * 16 + lg * 4] = pk;
            }
        }
    }
}

// ================= Kernel B: per-batch causal flash attention, no barriers =================
__global__ __launch_bounds__(512, 4) void attn_fused(
    const ushort* __restrict__ Kg, const ushort* __restrict__ Qg,
    const ushort* __restrict__ Vt, float* __restrict__ out)
{
    const int b   = blockIdx.x;
    const int tid = threadIdx.x;
    const int l   = tid & 63;
    const int w   = tid >> 6;
    const int l15 = l & 15;
    const int lg  = l >> 4;

    __shared__ ushort pb[8][16 * 40];
    ushort* pbw = pb[w];

    const ushort* Kb = Kg + (size_t)b * TT * HS;
    const ushort* Qb = Qg + (size_t)b * TT * HS;
    const ushort* Vb = Vt + (size_t)b * HS * TT;

    #pragma unroll
    for (int half = 0; half < 2; ++half) {
        const int rt = half ? (15 - w) : w;     // balanced causal work: 9 chunks/wave
        const int t0 = rt * 16;

        short8_t afr[2];
        afr[0] = *(const short8_t*)&Kb[(t0 + l15) * HS + lg * 8];
        afr[1] = *(const short8_t*)&Kb[(t0 + l15) * HS + 32 + lg * 8];

        float mr[4], lr[4];
        f32x4 o[4];
        #pragma unroll
        for (int r = 0; r < 4; ++r) { mr[r] = -INFINITY; lr[r] = 0.f; }
        #pragma unroll
        for (int nt = 0; nt < 4; ++nt) o[nt] = (f32x4){0.f, 0.f, 0.f, 0.f};

        const int jd = t0 >> 5;
        for (int j = 0; j <= jd; ++j) {
            const int sb = j * 32;
            f32x4 sacc[2];
            sacc[0] = (f32x4){0.f, 0.f, 0.f, 0.f};
            sacc[1] = (f32x4){0.f, 0.f, 0.f, 0.f};
            #pragma unroll
            for (int kk = 0; kk < 2; ++kk) {
                #pragma unroll
                for (int ct = 0; ct < 2; ++ct) {
                    short8_t bfr = *(const short8_t*)&Qb[(sb + ct * 16 + l15) * HS + kk * 32 + lg * 8];
                    sacc[ct] = __builtin_amdgcn_mfma_f32_16x16x32_bf16(afr[kk], bfr, sacc[ct], 0, 0, 0);
                }
            }
            #pragma unroll
            for (int ct = 0; ct < 2; ++ct) {
                int s = sb + ct * 16 + l15;
                #pragma unroll
                for (int r = 0; r < 4; ++r) {
                    int t = t0 + lg * 4 + r;
                    if (s > t) sacc[ct][r] = -INFINITY;
                }
            }
            float p0[4], p1[4], fsc[4];
            #pragma unroll
            for (int r = 0; r < 4; ++r) {
                float mx = fmaxf(sacc[0][r], sacc[1][r]);
                mx = fmaxf(mx, __shfl_xor(mx, 1));
                mx = fmaxf(mx, __shfl_xor(mx, 2));
                mx = fmaxf(mx, __shfl_xor(mx, 4));
                mx = fmaxf(mx, __shfl_xor(mx, 8));
                float nm = fmaxf(mr[r], mx);
                fsc[r] = __expf(mr[r] - nm);
                mr[r] = nm;
                p0[r] = __expf(sacc[0][r] - nm);
                p1[r] = __expf(sacc[1][r] - nm);
                float ps = p0[r] + p1[r];
                ps += __shfl_xor(ps, 1);
                ps += __shfl_xor(ps, 2);
                ps += __shfl_xor(ps, 4);
                ps += __shfl_xor(ps, 8);
                lr[r] = lr[r] * fsc[r] + ps;
            }
            #pragma unroll
            for (int nt = 0; nt < 4; ++nt)
                #pragma unroll
                for (int r = 0; r < 4; ++r) o[nt][r] *= fsc[r];
            #pragma unroll
            for (int r = 0; r < 4; ++r) {
                pbw[(lg * 4 + r) * 40 + l15]      = f2bf(p0[r]);
                pbw[(lg * 4 + r) * 40 + 16 + l15] = f2bf(p1[r]);
            }
            short8_t pa = *(const short8_t*)&pbw[l15 * 40 + lg * 8];
            #pragma unroll
            for (int nt = 0; nt < 4; ++nt) {
                short8_t bfr = *(const short8_t*)&Vb[(nt * 16 + l15) * TT + sb + lg * 8];
                o[nt] = __builtin_amdgcn_mfma_f32_16x16x32_bf16(pa, bfr, o[nt], 0, 0, 0);
            }
        }
        #pragma unroll
        for (int r = 0; r < 4; ++r) {
            float inv = 1.0f / lr[r];
            int t = t0 + lg * 4 + r;
            float* op = out + ((size_t)b * TT + t) * HS;
            #pragma unroll
            for (int nt = 0; nt < 4; ++nt)
                op[nt * 16 + l15] = o[nt][r] * inv;
        }
    }
}

extern "C" void kernel_launch(void* const* d_in, const int* in_sizes, int n_in,
                              void* d_out, int out_size, void* d_ws, size_t ws_size,
                              hipStream_t stream) {
    const float* x  = (const float*)d_in[0];
    const float* Wk = (const float*)d_in[1];
    const float* bk = (const float*)d_in[2];
    const float* Wq = (const float*)d_in[3];
    const float* bq = (const float*)d_in[4];
    const float* Wv = (const float*)d_in[5];
    const float* bv = (const float*)d_in[6];
    float* out = (float*)d_out;

    ushort* WTr = (ushort*)d_ws;
    ushort* Kg  = (ushort*)((char*)d_ws + K_OFF_B);
    ushort* Qg  = (ushort*)((char*)d_ws + Q_OFF_B);
    ushort* Vt  = (ushort*)((char*)d_ws + VT_OFF_B);

    prep_wtr<<<dim3(144), dim3(64), 0, stream>>>(Wk, Wq, Wv, WTr);
    proj_gemm<<<dim3(4096), dim3(256), 0, stream>>>(x, WTr, bk, bq, bv, Kg, Qg, Vt);
    attn_fused<<<dim3(BB), dim3(512), 0, stream>>>(Kg, Qg, Vt, out);
}